// Round 8
// baseline (6506.139 us; speedup 1.0000x reference)
//
#include <hip/hip_runtime.h>
#include <hip/hip_bf16.h>

// ---------------------------------------------------------------------------
// KiperwasserDependencyParser: embed -> bi-LSTM x2 -> pairwise MLP -> softmax
// Round 8: R7 scan + same-XCD L2 message path (sc0 stores/loads) with L3
// (sc0 sc1) fallback every 8th poll; parallel gate activations.
// ---------------------------------------------------------------------------

#define L2E 1.4426950408889634f

__device__ __forceinline__ float fast_rcp(float x) { return __builtin_amdgcn_rcpf(x); }
__device__ __forceinline__ float sigm_f(float x) {
    return fast_rcp(1.f + exp2f(-x * L2E));
}
__device__ __forceinline__ float tanh_f(float x) {
    return 1.f - 2.f * fast_rcp(1.f + exp2f(x * (2.f * L2E)));
}

// publish tagged 8B message: L2 copy (sc0) + write-through to L3 (sc0 sc1)
__device__ __forceinline__ void pub_msg(unsigned long long* p, unsigned long long m) {
    asm volatile(
        "global_store_dwordx2 %0, %1, off sc0\n\t"
        "global_store_dwordx2 %0, %1, off sc0 sc1"
        :: "v"(p), "v"(m) : "memory");
}
// poll loads: fast path hits the XCD L2; slow path bypasses to L3
__device__ __forceinline__ unsigned long long ld_l2(const unsigned long long* p) {
    unsigned long long r;
    asm volatile("global_load_dwordx2 %0, %1, off sc0\n\t"
                 "s_waitcnt vmcnt(0)"
                 : "=v"(r) : "v"(p) : "memory");
    return r;
}
__device__ __forceinline__ unsigned long long ld_l3(const unsigned long long* p) {
    unsigned long long r;
    asm volatile("global_load_dwordx2 %0, %1, off sc0 sc1\n\t"
                 "s_waitcnt vmcnt(0)"
                 : "=v"(r) : "v"(p) : "memory");
    return r;
}

// ----------------------------- embed ---------------------------------------
__global__ __launch_bounds__(256) void embed_kernel(
    const float* __restrict__ wt, const float* __restrict__ pt,
    const int* __restrict__ wi, const int* __restrict__ pi,
    float* __restrict__ x)
{
    int idx = blockIdx.x * 256 + threadIdx.x;
    if (idx >= 1024 * 576) return;
    int n = idx / 576, c = idx % 576;
    x[idx] = (c < 512) ? wt[wi[n] * 512 + c] : pt[pi[n] * 64 + (c - 512)];
}

// --------------------------- GEMM + bias ------------------------------------
__global__ __launch_bounds__(256) void gemm_bias(
    const float* __restrict__ A,
    const float* __restrict__ W0, const float* __restrict__ W1,
    const float* __restrict__ b0, const float* __restrict__ b1,
    float* __restrict__ C0, float* __restrict__ C1,
    int M, int N, int K)
{
    const float* W = blockIdx.z ? W1 : W0;
    const float* bias = blockIdx.z ? b1 : b0;
    float* C = blockIdx.z ? C1 : C0;
    int m0 = blockIdx.y * 64, n0 = blockIdx.x * 64;
    __shared__ float As[16][65];
    __shared__ float Ws[16][65];
    int tid = threadIdx.x;
    int tx = tid & 15, ty = tid >> 4;
    float acc[4][4] = {};
    int lr = tid >> 2, lkc = (tid & 3) * 4;
    for (int k0 = 0; k0 < K; k0 += 16) {
        float4 a4 = *(const float4*)&A[(size_t)(m0 + lr) * K + k0 + lkc];
        float4 w4 = *(const float4*)&W[(size_t)(n0 + lr) * K + k0 + lkc];
        As[lkc + 0][lr] = a4.x; As[lkc + 1][lr] = a4.y;
        As[lkc + 2][lr] = a4.z; As[lkc + 3][lr] = a4.w;
        Ws[lkc + 0][lr] = w4.x; Ws[lkc + 1][lr] = w4.y;
        Ws[lkc + 2][lr] = w4.z; Ws[lkc + 3][lr] = w4.w;
        __syncthreads();
#pragma unroll
        for (int k = 0; k < 16; k++) {
            float a[4], b[4];
#pragma unroll
            for (int i = 0; i < 4; i++) a[i] = As[k][ty * 4 + i];
#pragma unroll
            for (int j = 0; j < 4; j++) b[j] = Ws[k][tx * 4 + j];
#pragma unroll
            for (int i = 0; i < 4; i++)
#pragma unroll
                for (int j = 0; j < 4; j++) acc[i][j] += a[i] * b[j];
        }
        __syncthreads();
    }
    int colbase = n0 + tx * 4;
    float4 bv = *(const float4*)&bias[colbase];
#pragma unroll
    for (int i = 0; i < 4; i++) {
        float4 o;
        o.x = acc[i][0] + bv.x; o.y = acc[i][1] + bv.y;
        o.z = acc[i][2] + bv.z; o.w = acc[i][3] + bv.w;
        *(float4*)&C[(size_t)(m0 + ty * 4 + i) * N + colbase] = o;
    }
}

// ----------------------------- LSTM scan ------------------------------------
// 32 blocks; only slot 0 (dir0) and slot 4 (dir1) work -> 4 blocks/dir, each
// direction's blocks on ONE XCD under round-robin placement. 512 threads.
// Weights: 64 f32/thread in regs + 64 f32/thread in transposed LDS (as R7).
// Handoff: tagged {tag=t+1, h} 8B messages, depth-2 parity; dual-store
// (L2 + L3), dual-path poll (L2 fast, L3 every 8th) -- safe on any placement.
__global__ __launch_bounds__(512, 2) void lstm_scan(
    const float* __restrict__ xw_f, const float* __restrict__ xw_b,
    const float* __restrict__ Whh_f, const float* __restrict__ Whh_b,
    float* __restrict__ hout,                  // [1024][512]
    unsigned long long* __restrict__ hx)       // [2][4][4][2][64] tagged slots
{
    const int slot = blockIdx.x & 7;
    const int sub  = blockIdx.x >> 3;
    int dir;
    if (slot == 0) dir = 0;
    else if (slot == 4) dir = 1;
    else return;

    const float* __restrict__ xw  = dir ? xw_b : xw_f;
    const float* __restrict__ Whh = dir ? Whh_b : Whh_f;

    const int tid  = threadIdx.x;
    const int lane = tid & 63;
    const int wv   = tid >> 6;         // wave 0..7
    const int half = tid >> 8;         // k-half 0/1 (wave-uniform)
    const int lr   = tid & 255;        // local gate row 0..255
    const int gi   = lr >> 6;          // 0=i 1=f 2=g 3=o
    const int R    = gi * 256 + sub * 64 + (lr & 63);   // global gate row

    __shared__ float wlds[2][64][256]; // transposed weight store (128 KB)
    __shared__ float h_sh[256];
    __shared__ float part[512];
    __shared__ float gact[256];

    // ---- weights: k in [128h,128h+64) -> 16 float4 regs ----
    float4 wr[16];
    const float* Wrow = Whh + (size_t)R * 256 + (half << 7);
#pragma unroll
    for (int i = 0; i < 16; i++) wr[i] = ((const float4*)Wrow)[i];
    // ---- weights: k in [128h+64,128h+128) -> LDS transposed ----
#pragma unroll
    for (int kk = 0; kk < 64; kk++) wlds[half][kk][lr] = Wrow[64 + kk];

    if (tid < 256) h_sh[tid] = 0.f;    // h_0 = 0
    float c = 0.f;
    float xwv = (tid < 256) ? xw[(size_t)(dir ? 1023 : 0) * 1024 + R] : 0.f;
    __syncthreads();

    for (int t = 0; t < 1024; t++) {
        // ---- phase 1: dot over this thread's 128-k-slice ----
        float a0 = 0.f, a1 = 0.f, a2 = 0.f, a3 = 0.f;
        const float4* hp4 = (const float4*)&h_sh[half << 7];  // bcast reads
#pragma unroll
        for (int i = 0; i < 16; i += 4) {
            float4 h0 = hp4[i], h1 = hp4[i + 1], h2 = hp4[i + 2], h3 = hp4[i + 3];
            a0 += wr[i+0].x*h0.x + wr[i+0].y*h0.y + wr[i+0].z*h0.z + wr[i+0].w*h0.w;
            a1 += wr[i+1].x*h1.x + wr[i+1].y*h1.y + wr[i+1].z*h1.z + wr[i+1].w*h1.w;
            a2 += wr[i+2].x*h2.x + wr[i+2].y*h2.y + wr[i+2].z*h2.z + wr[i+2].w*h2.w;
            a3 += wr[i+3].x*h3.x + wr[i+3].y*h3.y + wr[i+3].z*h3.z + wr[i+3].w*h3.w;
        }
        const float* hb = &h_sh[(half << 7) + 64];            // bcast reads
#pragma unroll
        for (int kk = 0; kk < 64; kk += 4) {
            float h0 = hb[kk], h1 = hb[kk + 1], h2 = hb[kk + 2], h3 = hb[kk + 3];
            a0 += wlds[half][kk + 0][lr] * h0;
            a1 += wlds[half][kk + 1][lr] * h1;
            a2 += wlds[half][kk + 2][lr] * h2;
            a3 += wlds[half][kk + 3][lr] * h3;
        }
        part[tid] = ((a0 + a1) + (a2 + a3)) + (half ? 0.f : xwv);
        if (half == 0 && t + 1 < 1024) {
            int trown = dir ? (1022 - t) : (t + 1);
            xwv = xw[(size_t)trown * 1024 + R];   // prefetch, lands during sync
        }
        __syncthreads();                                      // b1

        // ---- phase 2: parallel gate activations (waves 0-3) ----
        if (tid < 256) {
            float s = part[tid] + part[256 + tid];
            gact[tid] = (gi == 2) ? tanh_f(s) : sigm_f(s);
        }
        __syncthreads();                                      // b2

        // ---- phase 3: c/h update + publish (wave 0) | poll (waves 1-3) ----
        if (tid < 64) {
            float iv = gact[lane], fv = gact[64 + lane],
                  gv = gact[128 + lane], ov = gact[192 + lane];
            c = fv * c + iv * gv;
            float h = ov * tanh_f(c);
            if (t + 1 < 1024) {
                unsigned long long msg =
                    ((unsigned long long)(unsigned)(t + 1) << 32) |
                    (unsigned long long)__float_as_uint(h);
                int par = (t + 1) & 1;
#pragma unroll
                for (int k = 1; k < 4; k++) {
                    int cc = (sub + k) & 3;
                    pub_msg(&hx[((((dir * 4 + cc) * 4 + sub) * 2 + par) << 6) + lane],
                            msg);
                }
            }
            h_sh[sub * 64 + lane] = h;            // own chunk via LDS
            int trow = dir ? (1023 - t) : t;
            hout[(size_t)trow * 512 + dir * 256 + sub * 64 + lane] = h;
        } else if (wv <= 3 && t + 1 < 1024) {
            int pw = (sub + wv) & 3;              // producer this wave tracks
            const unsigned long long* sp =
                &hx[((((dir * 4 + sub) * 4 + pw) * 2 + ((t + 1) & 1)) << 6) + lane];
            const unsigned want = (unsigned)(t + 1);
            unsigned long long v = ld_l2(sp);
            int it = 0;
            while ((unsigned)(v >> 32) != want) {
                ++it;
                v = ((it & 7) == 7) ? ld_l3(sp) : ld_l2(sp);
            }
            h_sh[pw * 64 + lane] = __uint_as_float((unsigned)v);
        }
        __syncthreads();                                      // b3

        // keep register weights live (scalar ties)
#pragma unroll
        for (int i = 0; i < 16; i++)
            asm volatile("" : "+v"(wr[i].x), "+v"(wr[i].y),
                              "+v"(wr[i].z), "+v"(wr[i].w));
    }
}

// ------------------------- transpose mlp_W1 ---------------------------------
__global__ __launch_bounds__(256) void transpose_w1(
    const float* __restrict__ W1, float* __restrict__ W1T)
{
    int idx = blockIdx.x * 256 + threadIdx.x;
    if (idx >= 100 * 1024) return;
    int n = idx / 1024, j = idx % 1024;
    W1T[j * 100 + n] = W1[idx];
}

// ---------------------- A = h1 Wh^T + b1, B = h1 Wm^T -----------------------
__global__ __launch_bounds__(256) void ab_kernel(
    const float* __restrict__ h1, const float* __restrict__ W1T,
    const float* __restrict__ b1v,
    float* __restrict__ Ab, float* __restrict__ Bb)
{
    int m0 = blockIdx.x * 16;
    __shared__ float hs[16][512];
    int tid = threadIdx.x;
    for (int idx = tid * 4; idx < 16 * 512; idx += 1024) {
        int r = idx >> 9, cc = idx & 511;
        *(float4*)&hs[r][cc] = *(const float4*)&h1[(size_t)(m0 + r) * 512 + cc];
    }
    __syncthreads();
    bool isB = tid >= 128;
    int n = tid & 127;
    if (n < 100) {
        float acc[16] = {};
        const float* wbase = W1T + (isB ? 512 * 100 : 0) + n;
#pragma unroll 4
        for (int k = 0; k < 512; k++) {
            float wv = wbase[k * 100];
#pragma unroll
            for (int m = 0; m < 16; m++) acc[m] += hs[m][k] * wv;
        }
        float badd = isB ? 0.f : b1v[n];
        float* dst = isB ? Bb : Ab;
#pragma unroll
        for (int m = 0; m < 16; m++) dst[(m0 + m) * 100 + n] = acc[m] + badd;
    }
}

// ------------------------------ pair MLP ------------------------------------
__global__ __launch_bounds__(256) void pair_kernel(
    const float* __restrict__ Ab, const float* __restrict__ Bb,
    const float* __restrict__ W2, const float* __restrict__ b2,
    float* __restrict__ sT)
{
    int i0 = blockIdx.x * 32, j0 = blockIdx.y * 32;
    __shared__ float Ash[32][101];
    __shared__ float Bsh[32][101];
    __shared__ float w2s[100];
    int tid = threadIdx.x;
    for (int idx = tid; idx < 3200; idx += 256) {
        int r = idx / 100, cc = idx % 100;
        Ash[r][cc] = Ab[(i0 + r) * 100 + cc];
        Bsh[r][cc] = Bb[(j0 + r) * 100 + cc];
    }
    if (tid < 100) w2s[tid] = W2[tid];
    __syncthreads();
    float b2v = b2[0];
    int il = (tid & 15) * 2, jl = (tid >> 4) * 2;
    float a00 = 0.f, a01 = 0.f, a10 = 0.f, a11 = 0.f;
#pragma unroll 4
    for (int k = 0; k < 100; k++) {
        float wv = w2s[k];
        float x0 = Ash[il][k], x1 = Ash[il + 1][k];
        float y0 = Bsh[jl][k], y1 = Bsh[jl + 1][k];
        a00 += wv * tanh_f(x0 + y0);
        a01 += wv * tanh_f(x0 + y1);
        a10 += wv * tanh_f(x1 + y0);
        a11 += wv * tanh_f(x1 + y1);
    }
    float vals[2][2] = {{a00, a01}, {a10, a11}};
#pragma unroll
    for (int a = 0; a < 2; a++)
#pragma unroll
        for (int b = 0; b < 2; b++) {
            int gi2 = i0 + il + a, gj = j0 + jl + b;
            float v = vals[a][b] + b2v;
            if (gi2 == gj) v = 0.f;
            sT[(size_t)gj * 1024 + gi2] = v;
        }
}

// ------------------------- column stats (softmax) ---------------------------
__global__ __launch_bounds__(256) void colstats(
    const float* __restrict__ sT, float* __restrict__ mx, float* __restrict__ rs)
{
    int j = blockIdx.x;
    const float* row = sT + (size_t)j * 1024;
    int tid = threadIdx.x;
    __shared__ float red[256];
    float m = -INFINITY;
    for (int i = tid; i < 1024; i += 256) m = fmaxf(m, row[i]);
    red[tid] = m; __syncthreads();
    for (int s = 128; s > 0; s >>= 1) {
        if (tid < s) red[tid] = fmaxf(red[tid], red[tid + s]);
        __syncthreads();
    }
    float mxv = red[0];
    __syncthreads();
    float ssum = 0.f;
    for (int i = tid; i < 1024; i += 256) ssum += exp2f((row[i] - mxv) * L2E);
    red[tid] = ssum; __syncthreads();
    for (int s = 128; s > 0; s >>= 1) {
        if (tid < s) red[tid] += red[tid + s];
        __syncthreads();
    }
    if (tid == 0) { mx[j] = mxv; rs[j] = 1.f / red[0]; }
}

// ----------------------- normalize + transpose write ------------------------
__global__ __launch_bounds__(256) void writeout(
    const float* __restrict__ sT, const float* __restrict__ mx,
    const float* __restrict__ rs, float* __restrict__ out)
{
    int i0 = blockIdx.x * 32, j0 = blockIdx.y * 32;
    __shared__ float til[32][33];
    int tid = threadIdx.x;
    int r = tid >> 3, c4 = (tid & 7) * 4;
    float4 v = *(const float4*)&sT[(size_t)(j0 + r) * 1024 + i0 + c4];
    til[r][c4 + 0] = v.x; til[r][c4 + 1] = v.y;
    til[r][c4 + 2] = v.z; til[r][c4 + 3] = v.w;
    __syncthreads();
    float4 o;
    float* op = &out[(size_t)(i0 + r) * 1024 + j0 + c4];
    o.x = exp2f((til[c4 + 0][r] - mx[j0 + c4 + 0]) * L2E) * rs[j0 + c4 + 0];
    o.y = exp2f((til[c4 + 1][r] - mx[j0 + c4 + 1]) * L2E) * rs[j0 + c4 + 1];
    o.z = exp2f((til[c4 + 2][r] - mx[j0 + c4 + 2]) * L2E) * rs[j0 + c4 + 2];
    o.w = exp2f((til[c4 + 3][r] - mx[j0 + c4 + 3]) * L2E) * rs[j0 + c4 + 3];
    *(float4*)op = o;
}

// ---------------------------------------------------------------------------
extern "C" void kernel_launch(void* const* d_in, const int* in_sizes, int n_in,
                              void* d_out, int out_size, void* d_ws, size_t ws_size,
                              hipStream_t stream)
{
    const float* word_table = (const float*)d_in[0];
    const float* pos_table  = (const float*)d_in[1];
    const float* l0f_Wih = (const float*)d_in[2];
    const float* l0f_Whh = (const float*)d_in[3];
    const float* l0f_b   = (const float*)d_in[4];
    const float* l0b_Wih = (const float*)d_in[5];
    const float* l0b_Whh = (const float*)d_in[6];
    const float* l0b_b   = (const float*)d_in[7];
    const float* l1f_Wih = (const float*)d_in[8];
    const float* l1f_Whh = (const float*)d_in[9];
    const float* l1f_b   = (const float*)d_in[10];
    const float* l1b_Wih = (const float*)d_in[11];
    const float* l1b_Whh = (const float*)d_in[12];
    const float* l1b_b   = (const float*)d_in[13];
    const float* mlp_W1  = (const float*)d_in[14];
    const float* mlp_b1  = (const float*)d_in[15];
    const float* mlp_W2  = (const float*)d_in[16];
    const float* mlp_b2  = (const float*)d_in[17];
    const int*   word_idx = (const int*)d_in[18];
    const int*   pos_idx  = (const int*)d_in[19];
    float* out = (float*)d_out;

    float* ws = (float*)d_ws;
    const size_t OFF_X   = 0;            // 1024*576
    const size_t OFF_XWF = 589824;       // 1024*1024
    const size_t OFF_XWB = 1638400;      // 1024*1024
    const size_t OFF_H0  = 2686976;      // 1024*512
    const size_t OFF_H1  = 3211264;      // 1024*512
    const size_t OFF_W1T = 3735552;      // 1024*100
    const size_t OFF_A   = 3837952;      // 1024*100
    const size_t OFF_B   = 3940352;      // 1024*100
    const size_t OFF_ST  = 4042752;      // 1024*1024
    const size_t OFF_MX  = 5091328;      // 1024
    const size_t OFF_RS  = 5092352;      // 1024
    const size_t OFF_HX  = 5095424;      // 2 scans * 4096 u64 (16384 floats)

    float* x   = ws + OFF_X;
    float* xwf = ws + OFF_XWF;
    float* xwb = ws + OFF_XWB;
    float* h0  = ws + OFF_H0;
    float* h1  = ws + OFF_H1;
    float* w1t = ws + OFF_W1T;
    float* Ab  = ws + OFF_A;
    float* Bb  = ws + OFF_B;
    float* sT  = ws + OFF_ST;
    float* mx  = ws + OFF_MX;
    float* rs  = ws + OFF_RS;
    unsigned long long* hx0 = (unsigned long long*)(ws + OFF_HX);
    unsigned long long* hx1 = hx0 + 4096;

    // zero tagged slots so graph replays never consume stale tags
    hipMemsetAsync(hx0, 0, 8192 * sizeof(unsigned long long), stream);

    embed_kernel<<<(1024 * 576 + 255) / 256, 256, 0, stream>>>(
        word_table, pos_table, word_idx, pos_idx, x);

    transpose_w1<<<(100 * 1024 + 255) / 256, 256, 0, stream>>>(mlp_W1, w1t);

    gemm_bias<<<dim3(16, 16, 2), 256, 0, stream>>>(
        x, l0f_Wih, l0b_Wih, l0f_b, l0b_b, xwf, xwb, 1024, 1024, 576);

    lstm_scan<<<32, 512, 0, stream>>>(
        xwf, xwb, l0f_Whh, l0b_Whh, h0, hx0);

    gemm_bias<<<dim3(16, 16, 2), 256, 0, stream>>>(
        h0, l1f_Wih, l1b_Wih, l1f_b, l1b_b, xwf, xwb, 1024, 1024, 512);

    lstm_scan<<<32, 512, 0, stream>>>(
        xwf, xwb, l1f_Whh, l1b_Whh, h1, hx1);

    ab_kernel<<<64, 256, 0, stream>>>(h1, w1t, mlp_b1, Ab, Bb);

    pair_kernel<<<dim3(32, 32), 256, 0, stream>>>(Ab, Bb, mlp_W2, mlp_b2, sT);

    colstats<<<1024, 256, 0, stream>>>(sT, mx, rs);

    writeout<<<dim3(32, 32), 256, 0, stream>>>(sT, mx, rs, out);
}

// Round 10
// 4237.361 us; speedup vs baseline: 1.5354x; 1.5354x over previous
//
#include <hip/hip_runtime.h>
#include <hip/hip_bf16.h>

// ---------------------------------------------------------------------------
// KiperwasserDependencyParser: embed -> bi-LSTM x2 -> pairwise MLP -> softmax
// Round 10: R5 base + fused tag|data 8B messages (kills the separate h-load
// round trip) + 4-deep pipelined sc0sc1 polls (RT/4 sample period), bounded
// with proven relaxed-agent fallback. 3 barriers/step.
// ---------------------------------------------------------------------------

#define L2E 1.4426950408889634f

__device__ __forceinline__ float fast_rcp(float x) { return __builtin_amdgcn_rcpf(x); }
__device__ __forceinline__ float sigm_f(float x) {
    return fast_rcp(1.f + exp2f(-x * L2E));
}
__device__ __forceinline__ float tanh_f(float x) {
    return 1.f - 2.f * fast_rcp(1.f + exp2f(x * (2.f * L2E)));
}

// publish tagged 8B message straight to the coherence point (L3).
// R8 proved: sc0 sc1 stores are observed by sc0 sc1 loads.
__device__ __forceinline__ void st_msg(unsigned long long* p, unsigned long long m) {
    asm volatile("global_store_dwordx2 %0, %1, off sc0 sc1"
                 :: "v"(p), "v"(m) : "memory");
}

// 4-deep pipelined poll of one 8B tagged slot; bounded, then falls back to
// the R5-proven relaxed-agent atomic loop. Wave-uniform exit via __all.
__device__ __forceinline__ unsigned long long poll_msg(
    const unsigned long long* p, unsigned want)
{
    unsigned long long r0, r1, r2, r3, r = 0;
    bool done = false;
    for (int it = 0; it < 8192 && !done; ++it) {
        asm volatile(
            "global_load_dwordx2 %0, %4, off sc0 sc1\n\t"
            "global_load_dwordx2 %1, %4, off sc0 sc1\n\t"
            "global_load_dwordx2 %2, %4, off sc0 sc1\n\t"
            "global_load_dwordx2 %3, %4, off sc0 sc1\n\t"
            "s_waitcnt vmcnt(3)"
            : "=&v"(r0), "=&v"(r1), "=&v"(r2), "=&v"(r3)
            : "v"(p) : "memory");
        if (__all((unsigned)(r0 >> 32) == want)) { r = r0; done = true; }
        if (!done) {
            asm volatile("s_waitcnt vmcnt(2)" ::: "memory");
            if (__all((unsigned)(r1 >> 32) == want)) { r = r1; done = true; }
        }
        if (!done) {
            asm volatile("s_waitcnt vmcnt(1)" ::: "memory");
            if (__all((unsigned)(r2 >> 32) == want)) { r = r2; done = true; }
        }
        if (!done) {
            asm volatile("s_waitcnt vmcnt(0)" ::: "memory");
            if (__all((unsigned)(r3 >> 32) == want)) { r = r3; done = true; }
        }
        asm volatile("s_waitcnt vmcnt(0)" ::: "memory");  // drain in-flight
    }
    if (!done) {   // guaranteed-terminating proven path (R5/R6/R7)
        do {
            r = __hip_atomic_load(p, __ATOMIC_RELAXED, __HIP_MEMORY_SCOPE_AGENT);
        } while (!__all((unsigned)(r >> 32) == want));
    }
    return r;
}

// ----------------------------- embed ---------------------------------------
__global__ __launch_bounds__(256) void embed_kernel(
    const float* __restrict__ wt, const float* __restrict__ pt,
    const int* __restrict__ wi, const int* __restrict__ pi,
    float* __restrict__ x)
{
    int idx = blockIdx.x * 256 + threadIdx.x;
    if (idx >= 1024 * 576) return;
    int n = idx / 576, c = idx % 576;
    x[idx] = (c < 512) ? wt[wi[n] * 512 + c] : pt[pi[n] * 64 + (c - 512)];
}

// --------------------------- GEMM + bias ------------------------------------
__global__ __launch_bounds__(256) void gemm_bias(
    const float* __restrict__ A,
    const float* __restrict__ W0, const float* __restrict__ W1,
    const float* __restrict__ b0, const float* __restrict__ b1,
    float* __restrict__ C0, float* __restrict__ C1,
    int M, int N, int K)
{
    const float* W = blockIdx.z ? W1 : W0;
    const float* bias = blockIdx.z ? b1 : b0;
    float* C = blockIdx.z ? C1 : C0;
    int m0 = blockIdx.y * 64, n0 = blockIdx.x * 64;
    __shared__ float As[16][65];
    __shared__ float Ws[16][65];
    int tid = threadIdx.x;
    int tx = tid & 15, ty = tid >> 4;
    float acc[4][4] = {};
    int lr = tid >> 2, lkc = (tid & 3) * 4;
    for (int k0 = 0; k0 < K; k0 += 16) {
        float4 a4 = *(const float4*)&A[(size_t)(m0 + lr) * K + k0 + lkc];
        float4 w4 = *(const float4*)&W[(size_t)(n0 + lr) * K + k0 + lkc];
        As[lkc + 0][lr] = a4.x; As[lkc + 1][lr] = a4.y;
        As[lkc + 2][lr] = a4.z; As[lkc + 3][lr] = a4.w;
        Ws[lkc + 0][lr] = w4.x; Ws[lkc + 1][lr] = w4.y;
        Ws[lkc + 2][lr] = w4.z; Ws[lkc + 3][lr] = w4.w;
        __syncthreads();
#pragma unroll
        for (int k = 0; k < 16; k++) {
            float a[4], b[4];
#pragma unroll
            for (int i = 0; i < 4; i++) a[i] = As[k][ty * 4 + i];
#pragma unroll
            for (int j = 0; j < 4; j++) b[j] = Ws[k][tx * 4 + j];
#pragma unroll
            for (int i = 0; i < 4; i++)
#pragma unroll
                for (int j = 0; j < 4; j++) acc[i][j] += a[i] * b[j];
        }
        __syncthreads();
    }
    int colbase = n0 + tx * 4;
    float4 bv = *(const float4*)&bias[colbase];
#pragma unroll
    for (int i = 0; i < 4; i++) {
        float4 o;
        o.x = acc[i][0] + bv.x; o.y = acc[i][1] + bv.y;
        o.z = acc[i][2] + bv.z; o.w = acc[i][3] + bv.w;
        *(float4*)&C[(size_t)(m0 + ty * 4 + i) * N + colbase] = o;
    }
}

// ----------------------------- LSTM scan ------------------------------------
// 4 blocks/direction (slots 0 and 4 of 8), 512 threads (8 waves, 2/SIMD).
// Block `sub` owns h[64*sub..64*sub+64): 256 gate rows, 2 threads/row
// (k-halves of 128); 128 weight f32/thread pinned (R5-proven).
// Handoff: fused {tag=t+1 | h} 8B messages, one slot per (producer,parity),
// published with sc0 sc1 stores; consumers (waves 1-3) poll with 4-deep
// pipelined sc0 sc1 loads (bounded + proven fallback). 3 barriers/step.
__global__ __launch_bounds__(512, 2) void lstm_scan(
    const float* __restrict__ xw_f, const float* __restrict__ xw_b,
    const float* __restrict__ Whh_f, const float* __restrict__ Whh_b,
    float* __restrict__ hout,              // [1024][512]
    unsigned long long* __restrict__ hx)   // [dir][prod 4][par 2][64] slots
{
    int slot = blockIdx.x & 7;
    int sub  = blockIdx.x >> 3;
    int dir;
    if (slot == 0) dir = 0;
    else if (slot == 4) dir = 1;
    else return;

    const float* __restrict__ xw  = dir ? xw_b : xw_f;
    const float* __restrict__ Whh = dir ? Whh_b : Whh_f;
    unsigned long long* __restrict__ hxd = hx + dir * 512;

    const int tid  = threadIdx.x;
    const int lane = tid & 63;
    const int wv   = tid >> 6;         // wave 0..7
    const int half = tid >> 8;         // k-half 0,1 (wave-uniform)
    const int lr   = tid & 255;        // local gate row
    const int gi   = lr >> 6;          // 0=i 1=f 2=g 3=o
    const int R    = gi * 256 + (sub << 6) + (lr & 63);   // global gate row

    // ---- weights into registers: 128 f32 = 32 float4 (R5-proven) ----
    float4 w4[32];
    {
        const float4* Wr = (const float4*)(Whh + (size_t)R * 256 + (half << 7));
#pragma unroll
        for (int i = 0; i < 32; i++) w4[i] = Wr[i];
    }

    __shared__ float h_sh[256];
    __shared__ float part[512];
    __shared__ float gact[256];

    float c = 0.f;
    float xwv = 0.f;
    if (tid < 256) xwv = xw[(size_t)(dir ? 1023 : 0) * 1024 + R];
    if (wv < 4) h_sh[(wv << 6) + lane] = 0.f;   // h_0 = 0
    __syncthreads();

    for (int t = 0; t < 1024; t++) {
        // ---- phase 1: 128-FMA dot over this thread's k-half ----
        float a0 = 0.f, a1 = 0.f, a2 = 0.f, a3 = 0.f;
        const float4* hp4 = (const float4*)&h_sh[half << 7];  // bcast reads
#pragma unroll
        for (int i = 0; i < 32; i += 4) {
            float4 h0v = hp4[i + 0], w0v = w4[i + 0];
            float4 h1v = hp4[i + 1], w1v = w4[i + 1];
            float4 h2v = hp4[i + 2], w2v = w4[i + 2];
            float4 h3v = hp4[i + 3], w3v = w4[i + 3];
            a0 += w0v.x * h0v.x + w0v.y * h0v.y + w0v.z * h0v.z + w0v.w * h0v.w;
            a1 += w1v.x * h1v.x + w1v.y * h1v.y + w1v.z * h1v.z + w1v.w * h1v.w;
            a2 += w2v.x * h2v.x + w2v.y * h2v.y + w2v.z * h2v.z + w2v.w * h2v.w;
            a3 += w3v.x * h3v.x + w3v.y * h3v.y + w3v.z * h3v.z + w3v.w * h3v.w;
        }
        part[tid] = (a0 + a1) + (a2 + a3);
        __syncthreads();                                      // b1

        // ---- phase 2: gate activations (4 waves) + xw prefetch ----
        if (tid < 256) {
            float s = part[tid] + part[tid + 256] + xwv;
            gact[tid] = (gi == 2) ? tanh_f(s) : sigm_f(s);
            if (t + 1 < 1024) {
                int trown = dir ? (1022 - t) : (t + 1);
                xwv = xw[(size_t)trown * 1024 + R];
            }
        }
        __syncthreads();                                      // b2

        // ---- phase 3: c/h + publish (wave 0) | poll (waves 1-3) ----
        if (tid < 64) {
            float iv = gact[lane], fv = gact[64 + lane],
                  gv = gact[128 + lane], ov = gact[192 + lane];
            c = fv * c + iv * gv;
            float h = ov * tanh_f(c);
            if (t + 1 < 1024) {
                unsigned long long msg =
                    ((unsigned long long)(unsigned)(t + 1) << 32) |
                    (unsigned long long)__float_as_uint(h);
                st_msg(&hxd[(((sub << 1) + ((t + 1) & 1)) << 6) + lane], msg);
                h_sh[(sub << 6) + lane] = h;   // own chunk via LDS
            }
            int trow = dir ? (1023 - t) : t;
            hout[(size_t)trow * 512 + dir * 256 + (sub << 6) + lane] = h;
        } else if (wv <= 3 && t + 1 < 1024) {
            int pw = (sub + wv) & 3;           // producer this wave tracks
            const unsigned long long* sp =
                &hxd[(((pw << 1) + ((t + 1) & 1)) << 6) + lane];
            unsigned long long v = poll_msg(sp, (unsigned)(t + 1));
            h_sh[(pw << 6) + lane] = __uint_as_float((unsigned)v);
        }
        __syncthreads();                                      // b3

        // keep register weights live (scalar ties; R5-proven)
#pragma unroll
        for (int i = 0; i < 32; i++)
            asm volatile("" : "+v"(w4[i].x), "+v"(w4[i].y),
                              "+v"(w4[i].z), "+v"(w4[i].w));
    }
}

// ------------------------- transpose mlp_W1 ---------------------------------
__global__ __launch_bounds__(256) void transpose_w1(
    const float* __restrict__ W1, float* __restrict__ W1T)
{
    int idx = blockIdx.x * 256 + threadIdx.x;
    if (idx >= 100 * 1024) return;
    int n = idx / 1024, j = idx % 1024;
    W1T[j * 100 + n] = W1[idx];
}

// ---------------------- A = h1 Wh^T + b1, B = h1 Wm^T -----------------------
__global__ __launch_bounds__(256) void ab_kernel(
    const float* __restrict__ h1, const float* __restrict__ W1T,
    const float* __restrict__ b1v,
    float* __restrict__ Ab, float* __restrict__ Bb)
{
    int m0 = blockIdx.x * 16;
    __shared__ float hs[16][512];
    int tid = threadIdx.x;
    for (int idx = tid * 4; idx < 16 * 512; idx += 1024) {
        int r = idx >> 9, cc = idx & 511;
        *(float4*)&hs[r][cc] = *(const float4*)&h1[(size_t)(m0 + r) * 512 + cc];
    }
    __syncthreads();
    bool isB = tid >= 128;
    int n = tid & 127;
    if (n < 100) {
        float acc[16] = {};
        const float* wbase = W1T + (isB ? 512 * 100 : 0) + n;
#pragma unroll 4
        for (int k = 0; k < 512; k++) {
            float wv = wbase[k * 100];
#pragma unroll
            for (int m = 0; m < 16; m++) acc[m] += hs[m][k] * wv;
        }
        float badd = isB ? 0.f : b1v[n];
        float* dst = isB ? Bb : Ab;
#pragma unroll
        for (int m = 0; m < 16; m++) dst[(m0 + m) * 100 + n] = acc[m] + badd;
    }
}

// ------------------------------ pair MLP ------------------------------------
__global__ __launch_bounds__(256) void pair_kernel(
    const float* __restrict__ Ab, const float* __restrict__ Bb,
    const float* __restrict__ W2, const float* __restrict__ b2,
    float* __restrict__ sT)
{
    int i0 = blockIdx.x * 32, j0 = blockIdx.y * 32;
    __shared__ float Ash[32][101];
    __shared__ float Bsh[32][101];
    __shared__ float w2s[100];
    int tid = threadIdx.x;
    for (int idx = tid; idx < 3200; idx += 256) {
        int r = idx / 100, cc = idx % 100;
        Ash[r][cc] = Ab[(i0 + r) * 100 + cc];
        Bsh[r][cc] = Bb[(j0 + r) * 100 + cc];
    }
    if (tid < 100) w2s[tid] = W2[tid];
    __syncthreads();
    float b2v = b2[0];
    int il = (tid & 15) * 2, jl = (tid >> 4) * 2;
    float a00 = 0.f, a01 = 0.f, a10 = 0.f, a11 = 0.f;
#pragma unroll 4
    for (int k = 0; k < 100; k++) {
        float wv = w2s[k];
        float x0 = Ash[il][k], x1 = Ash[il + 1][k];
        float y0 = Bsh[jl][k], y1 = Bsh[jl + 1][k];
        a00 += wv * tanh_f(x0 + y0);
        a01 += wv * tanh_f(x0 + y1);
        a10 += wv * tanh_f(x1 + y0);
        a11 += wv * tanh_f(x1 + y1);
    }
    float vals[2][2] = {{a00, a01}, {a10, a11}};
#pragma unroll
    for (int a = 0; a < 2; a++)
#pragma unroll
        for (int b = 0; b < 2; b++) {
            int gi2 = i0 + il + a, gj = j0 + jl + b;
            float v = vals[a][b] + b2v;
            if (gi2 == gj) v = 0.f;
            sT[(size_t)gj * 1024 + gi2] = v;
        }
}

// ------------------------- column stats (softmax) ---------------------------
__global__ __launch_bounds__(256) void colstats(
    const float* __restrict__ sT, float* __restrict__ mx, float* __restrict__ rs)
{
    int j = blockIdx.x;
    const float* row = sT + (size_t)j * 1024;
    int tid = threadIdx.x;
    __shared__ float red[256];
    float m = -INFINITY;
    for (int i = tid; i < 1024; i += 256) m = fmaxf(m, row[i]);
    red[tid] = m; __syncthreads();
    for (int s = 128; s > 0; s >>= 1) {
        if (tid < s) red[tid] = fmaxf(red[tid], red[tid + s]);
        __syncthreads();
    }
    float mxv = red[0];
    __syncthreads();
    float ssum = 0.f;
    for (int i = tid; i < 1024; i += 256) ssum += exp2f((row[i] - mxv) * L2E);
    red[tid] = ssum; __syncthreads();
    for (int s = 128; s > 0; s >>= 1) {
        if (tid < s) red[tid] += red[tid + s];
        __syncthreads();
    }
    if (tid == 0) { mx[j] = mxv; rs[j] = 1.f / red[0]; }
}

// ----------------------- normalize + transpose write ------------------------
__global__ __launch_bounds__(256) void writeout(
    const float* __restrict__ sT, const float* __restrict__ mx,
    const float* __restrict__ rs, float* __restrict__ out)
{
    int i0 = blockIdx.x * 32, j0 = blockIdx.y * 32;
    __shared__ float til[32][33];
    int tid = threadIdx.x;
    int r = tid >> 3, c4 = (tid & 7) * 4;
    float4 v = *(const float4*)&sT[(size_t)(j0 + r) * 1024 + i0 + c4];
    til[r][c4 + 0] = v.x; til[r][c4 + 1] = v.y;
    til[r][c4 + 2] = v.z; til[r][c4 + 3] = v.w;
    __syncthreads();
    float4 o;
    float* op = &out[(size_t)(i0 + r) * 1024 + j0 + c4];
    o.x = exp2f((til[c4 + 0][r] - mx[j0 + c4 + 0]) * L2E) * rs[j0 + c4 + 0];
    o.y = exp2f((til[c4 + 1][r] - mx[j0 + c4 + 1]) * L2E) * rs[j0 + c4 + 1];
    o.z = exp2f((til[c4 + 2][r] - mx[j0 + c4 + 2]) * L2E) * rs[j0 + c4 + 2];
    o.w = exp2f((til[c4 + 3][r] - mx[j0 + c4 + 3]) * L2E) * rs[j0 + c4 + 3];
    *(float4*)op = o;
}

// ---------------------------------------------------------------------------
extern "C" void kernel_launch(void* const* d_in, const int* in_sizes, int n_in,
                              void* d_out, int out_size, void* d_ws, size_t ws_size,
                              hipStream_t stream)
{
    const float* word_table = (const float*)d_in[0];
    const float* pos_table  = (const float*)d_in[1];
    const float* l0f_Wih = (const float*)d_in[2];
    const float* l0f_Whh = (const float*)d_in[3];
    const float* l0f_b   = (const float*)d_in[4];
    const float* l0b_Wih = (const float*)d_in[5];
    const float* l0b_Whh = (const float*)d_in[6];
    const float* l0b_b   = (const float*)d_in[7];
    const float* l1f_Wih = (const float*)d_in[8];
    const float* l1f_Whh = (const float*)d_in[9];
    const float* l1f_b   = (const float*)d_in[10];
    const float* l1b_Wih = (const float*)d_in[11];
    const float* l1b_Whh = (const float*)d_in[12];
    const float* l1b_b   = (const float*)d_in[13];
    const float* mlp_W1  = (const float*)d_in[14];
    const float* mlp_b1  = (const float*)d_in[15];
    const float* mlp_W2  = (const float*)d_in[16];
    const float* mlp_b2  = (const float*)d_in[17];
    const int*   word_idx = (const int*)d_in[18];
    const int*   pos_idx  = (const int*)d_in[19];
    float* out = (float*)d_out;

    float* ws = (float*)d_ws;
    const size_t OFF_X   = 0;            // 1024*576
    const size_t OFF_XWF = 589824;       // 1024*1024
    const size_t OFF_XWB = 1638400;      // 1024*1024
    const size_t OFF_H0  = 2686976;      // 1024*512
    const size_t OFF_H1  = 3211264;      // 1024*512
    const size_t OFF_W1T = 3735552;      // 1024*100
    const size_t OFF_A   = 3837952;      // 1024*100
    const size_t OFF_B   = 3940352;      // 1024*100
    const size_t OFF_ST  = 4042752;      // 1024*1024
    const size_t OFF_MX  = 5091328;      // 1024
    const size_t OFF_RS  = 5092352;      // 1024
    const size_t OFF_HX  = 5095424;      // 2 scans * 1024 u64 (= 4096 floats)

    float* x   = ws + OFF_X;
    float* xwf = ws + OFF_XWF;
    float* xwb = ws + OFF_XWB;
    float* h0  = ws + OFF_H0;
    float* h1  = ws + OFF_H1;
    float* w1t = ws + OFF_W1T;
    float* Ab  = ws + OFF_A;
    float* Bb  = ws + OFF_B;
    float* sT  = ws + OFF_ST;
    float* mx  = ws + OFF_MX;
    float* rs  = ws + OFF_RS;
    unsigned long long* hx0 = (unsigned long long*)(ws + OFF_HX);
    unsigned long long* hx1 = hx0 + 1024;

    // zero tagged slots so replays never consume stale tags
    hipMemsetAsync(hx0, 0, 2048 * sizeof(unsigned long long), stream);

    embed_kernel<<<(1024 * 576 + 255) / 256, 256, 0, stream>>>(
        word_table, pos_table, word_idx, pos_idx, x);

    transpose_w1<<<(100 * 1024 + 255) / 256, 256, 0, stream>>>(mlp_W1, w1t);

    gemm_bias<<<dim3(16, 16, 2), 256, 0, stream>>>(
        x, l0f_Wih, l0b_Wih, l0f_b, l0b_b, xwf, xwb, 1024, 1024, 576);

    lstm_scan<<<32, 512, 0, stream>>>(
        xwf, xwb, l0f_Whh, l0b_Whh, h0, hx0);

    gemm_bias<<<dim3(16, 16, 2), 256, 0, stream>>>(
        h0, l1f_Wih, l1b_Wih, l1f_b, l1b_b, xwf, xwb, 1024, 1024, 512);

    lstm_scan<<<32, 512, 0, stream>>>(
        xwf, xwb, l1f_Whh, l1b_Whh, h1, hx1);

    ab_kernel<<<64, 256, 0, stream>>>(h1, w1t, mlp_b1, Ab, Bb);

    pair_kernel<<<dim3(32, 32), 256, 0, stream>>>(Ab, Bb, mlp_W2, mlp_b2, sT);

    colstats<<<1024, 256, 0, stream>>>(sT, mx, rs);

    writeout<<<dim3(32, 32), 256, 0, stream>>>(sT, mx, rs, out);
}

// Round 11
// 4086.982 us; speedup vs baseline: 1.5919x; 1.0368x over previous
//
#include <hip/hip_runtime.h>
#include <hip/hip_bf16.h>

// ---------------------------------------------------------------------------
// KiperwasserDependencyParser: embed -> bi-LSTM x2 -> pairwise MLP -> softmax
// Round 11: dual-direction scan blocks (8 blocks, waves 0-3 dir0, 4-7 dir1),
// combined 64-lane message slots (dir0 lanes 0-31, dir1 lanes 32-63),
// 3 barriers/step TOTAL for both dirs; R10-proven messaging primitives.
// ---------------------------------------------------------------------------

#define L2E 1.4426950408889634f

__device__ __forceinline__ float fast_rcp(float x) { return __builtin_amdgcn_rcpf(x); }
__device__ __forceinline__ float sigm_f(float x) {
    return fast_rcp(1.f + exp2f(-x * L2E));
}
__device__ __forceinline__ float tanh_f(float x) {
    return 1.f - 2.f * fast_rcp(1.f + exp2f(x * (2.f * L2E)));
}

// publish tagged 8B message to the coherence point (R10-proven visible to
// sc0 sc1 loads and to relaxed agent atomic loads).
__device__ __forceinline__ void st_msg(unsigned long long* p, unsigned long long m) {
    asm volatile("global_store_dwordx2 %0, %1, off sc0 sc1"
                 :: "v"(p), "v"(m) : "memory");
}

// 4-deep pipelined poll of one 8B tagged slot; bounded, then falls back to
// the proven relaxed-agent atomic loop. Wave-uniform exit via __all.
// (byte-identical to R10's measured-good version)
__device__ __forceinline__ unsigned long long poll_msg(
    const unsigned long long* p, unsigned want)
{
    unsigned long long r0, r1, r2, r3, r = 0;
    bool done = false;
    for (int it = 0; it < 8192 && !done; ++it) {
        asm volatile(
            "global_load_dwordx2 %0, %4, off sc0 sc1\n\t"
            "global_load_dwordx2 %1, %4, off sc0 sc1\n\t"
            "global_load_dwordx2 %2, %4, off sc0 sc1\n\t"
            "global_load_dwordx2 %3, %4, off sc0 sc1\n\t"
            "s_waitcnt vmcnt(3)"
            : "=&v"(r0), "=&v"(r1), "=&v"(r2), "=&v"(r3)
            : "v"(p) : "memory");
        if (__all((unsigned)(r0 >> 32) == want)) { r = r0; done = true; }
        if (!done) {
            asm volatile("s_waitcnt vmcnt(2)" ::: "memory");
            if (__all((unsigned)(r1 >> 32) == want)) { r = r1; done = true; }
        }
        if (!done) {
            asm volatile("s_waitcnt vmcnt(1)" ::: "memory");
            if (__all((unsigned)(r2 >> 32) == want)) { r = r2; done = true; }
        }
        if (!done) {
            asm volatile("s_waitcnt vmcnt(0)" ::: "memory");
            if (__all((unsigned)(r3 >> 32) == want)) { r = r3; done = true; }
        }
        asm volatile("s_waitcnt vmcnt(0)" ::: "memory");  // drain in-flight
    }
    if (!done) {   // guaranteed-terminating proven path
        do {
            r = __hip_atomic_load(p, __ATOMIC_RELAXED, __HIP_MEMORY_SCOPE_AGENT);
        } while (!__all((unsigned)(r >> 32) == want));
    }
    return r;
}

// ----------------------------- embed ---------------------------------------
__global__ __launch_bounds__(256) void embed_kernel(
    const float* __restrict__ wt, const float* __restrict__ pt,
    const int* __restrict__ wi, const int* __restrict__ pi,
    float* __restrict__ x)
{
    int idx = blockIdx.x * 256 + threadIdx.x;
    if (idx >= 1024 * 576) return;
    int n = idx / 576, c = idx % 576;
    x[idx] = (c < 512) ? wt[wi[n] * 512 + c] : pt[pi[n] * 64 + (c - 512)];
}

// --------------------------- GEMM + bias ------------------------------------
__global__ __launch_bounds__(256) void gemm_bias(
    const float* __restrict__ A,
    const float* __restrict__ W0, const float* __restrict__ W1,
    const float* __restrict__ b0, const float* __restrict__ b1,
    float* __restrict__ C0, float* __restrict__ C1,
    int M, int N, int K)
{
    const float* W = blockIdx.z ? W1 : W0;
    const float* bias = blockIdx.z ? b1 : b0;
    float* C = blockIdx.z ? C1 : C0;
    int m0 = blockIdx.y * 64, n0 = blockIdx.x * 64;
    __shared__ float As[16][65];
    __shared__ float Ws[16][65];
    int tid = threadIdx.x;
    int tx = tid & 15, ty = tid >> 4;
    float acc[4][4] = {};
    int lr = tid >> 2, lkc = (tid & 3) * 4;
    for (int k0 = 0; k0 < K; k0 += 16) {
        float4 a4 = *(const float4*)&A[(size_t)(m0 + lr) * K + k0 + lkc];
        float4 w4 = *(const float4*)&W[(size_t)(n0 + lr) * K + k0 + lkc];
        As[lkc + 0][lr] = a4.x; As[lkc + 1][lr] = a4.y;
        As[lkc + 2][lr] = a4.z; As[lkc + 3][lr] = a4.w;
        Ws[lkc + 0][lr] = w4.x; Ws[lkc + 1][lr] = w4.y;
        Ws[lkc + 2][lr] = w4.z; Ws[lkc + 3][lr] = w4.w;
        __syncthreads();
#pragma unroll
        for (int k = 0; k < 16; k++) {
            float a[4], b[4];
#pragma unroll
            for (int i = 0; i < 4; i++) a[i] = As[k][ty * 4 + i];
#pragma unroll
            for (int j = 0; j < 4; j++) b[j] = Ws[k][tx * 4 + j];
#pragma unroll
            for (int i = 0; i < 4; i++)
#pragma unroll
                for (int j = 0; j < 4; j++) acc[i][j] += a[i] * b[j];
        }
        __syncthreads();
    }
    int colbase = n0 + tx * 4;
    float4 bv = *(const float4*)&bias[colbase];
#pragma unroll
    for (int i = 0; i < 4; i++) {
        float4 o;
        o.x = acc[i][0] + bv.x; o.y = acc[i][1] + bv.y;
        o.z = acc[i][2] + bv.z; o.w = acc[i][3] + bv.w;
        *(float4*)&C[(size_t)(m0 + ty * 4 + i) * N + colbase] = o;
    }
}

// ----------------------------- LSTM scan ------------------------------------
// 8 blocks; block `sub` owns h[32*sub..32*sub+32) of BOTH directions.
// Threads 0-255 compute dir0 (fwd), 256-511 dir1 (bwd): per dir 128 gate
// rows x 2 k-halves -> 64 weight f32/thread (16 float4, scalar-pinned).
// Wave 0 = dir0 producer, wave 4 = dir1 producer; both publish tag|h into
// ONE combined slot[prod][parity][64] (lanes 0-31 dir0, 32-63 dir1).
// Waves 1-7 each poll one remote producer's combined slot (64 lanes, both
// dirs in one __all). 3 barriers/step covering BOTH directions.
__global__ __launch_bounds__(512, 2) void lstm_scan(
    const float* __restrict__ xw_f, const float* __restrict__ xw_b,
    const float* __restrict__ Whh_f, const float* __restrict__ Whh_b,
    float* __restrict__ hout,              // [1024][512]
    unsigned long long* __restrict__ hx)   // [prod 8][par 2][64] slots
{
    const int sub  = blockIdx.x;           // 0..7
    const int tid  = threadIdx.x;
    const int lane = tid & 63;
    const int wv   = tid >> 6;             // wave 0..7
    const int dsel = tid >> 8;             // 0: dir0 threads, 1: dir1 threads
    const int tl   = tid & 255;            // local id within dir group
    const int kh   = tl >> 7;              // k-half 0/1 (wave-uniform)
    const int lrow = tl & 127;             // local gate row 0..127
    const int gi   = lrow >> 5;            // 0=i 1=f 2=g 3=o
    const int R    = gi * 256 + sub * 32 + (lrow & 31);   // global gate row

    const float* __restrict__ xw  = dsel ? xw_b : xw_f;
    const float* __restrict__ Whh = dsel ? Whh_b : Whh_f;

    // ---- weights: this dir's 64 f32 slice -> 16 float4 registers ----
    float4 w4[16];
    {
        const float4* Wr = (const float4*)(Whh + (size_t)R * 256 + (kh << 7));
#pragma unroll
        for (int i = 0; i < 16; i++) w4[i] = Wr[i];
    }

    __shared__ float h0_sh[256], h1_sh[256];
    __shared__ float part0[256], part1[256];
    __shared__ float gact0[128], gact1[128];
    float* __restrict__ h_sh  = dsel ? h1_sh : h0_sh;
    float* __restrict__ partd = dsel ? part1 : part0;
    float* __restrict__ gactd = dsel ? gact1 : gact0;

    float c = 0.f;                         // live in waves 0 and 4, lanes<32
    float xwv = 0.f;
    if (tl < 128) xwv = xw[(size_t)(dsel ? 1023 : 0) * 1024 + R];
    if (tid < 256) { h0_sh[tid] = 0.f; h1_sh[tid] = 0.f; }   // h_0 = 0
    __syncthreads();

    for (int t = 0; t < 1024; t++) {
        // ---- phase 1: 64-MAC dot over this thread's k-half (both dirs) ----
        float a0 = 0.f, a1 = 0.f, a2 = 0.f, a3 = 0.f;
        const float4* hp4 = (const float4*)&h_sh[kh << 7];   // bcast reads
#pragma unroll
        for (int i = 0; i < 16; i += 4) {
            float4 h0v = hp4[i + 0], w0v = w4[i + 0];
            float4 h1v = hp4[i + 1], w1v = w4[i + 1];
            float4 h2v = hp4[i + 2], w2v = w4[i + 2];
            float4 h3v = hp4[i + 3], w3v = w4[i + 3];
            a0 += w0v.x * h0v.x + w0v.y * h0v.y + w0v.z * h0v.z + w0v.w * h0v.w;
            a1 += w1v.x * h1v.x + w1v.y * h1v.y + w1v.z * h1v.z + w1v.w * h1v.w;
            a2 += w2v.x * h2v.x + w2v.y * h2v.y + w2v.z * h2v.z + w2v.w * h2v.w;
            a3 += w3v.x * h3v.x + w3v.y * h3v.y + w3v.z * h3v.z + w3v.w * h3v.w;
        }
        partd[tl] = (a0 + a1) + (a2 + a3);
        __syncthreads();                                     // B1

        // ---- phase 2: gate activations (both dirs) + xw prefetch ----
        if (tl < 128) {
            float s = partd[tl] + partd[128 + tl] + xwv;
            gactd[tl] = (gi == 2) ? tanh_f(s) : sigm_f(s);
            if (t + 1 < 1024) {
                int trown = dsel ? (1022 - t) : (t + 1);
                xwv = xw[(size_t)trown * 1024 + R];
            }
        }
        __syncthreads();                                     // B2

        // ---- phase 3: producers (waves 0,4) c/h+publish; waves 1-7 poll ----
        const int par = (t + 1) & 1;
        if (wv == 0 || wv == 4) {
            if (lane < 32) {
                float iv = gactd[lane], fv = gactd[32 + lane],
                      gv = gactd[64 + lane], ov = gactd[96 + lane];
                c = fv * c + iv * gv;
                float h = ov * tanh_f(c);
                if (t + 1 < 1024) {
                    unsigned long long msg =
                        ((unsigned long long)(unsigned)(t + 1) << 32) |
                        (unsigned long long)__float_as_uint(h);
                    st_msg(&hx[(((sub << 1) + par) << 6) + (dsel << 5) + lane], msg);
                    h_sh[sub * 32 + lane] = h;   // own chunk via LDS
                }
                int trow = dsel ? (1023 - t) : t;
                hout[(size_t)trow * 512 + (dsel << 8) + sub * 32 + lane] = h;
            }
        }
        if (wv != 0 && t + 1 < 1024) {
            int pw = (sub + wv) & 7;          // producer block this wave tracks
            const unsigned long long* sp =
                &hx[(((pw << 1) + par) << 6) + lane];        // both dir halves
            unsigned long long v = poll_msg(sp, (unsigned)(t + 1));
            float hv = __uint_as_float((unsigned)v);
            ((lane < 32) ? h0_sh : h1_sh)[pw * 32 + (lane & 31)] = hv;
        }
        __syncthreads();                                     // B3

        // keep weights register-resident (scalar ties; proven R5/R10)
#pragma unroll
        for (int i = 0; i < 16; i++)
            asm volatile("" : "+v"(w4[i].x), "+v"(w4[i].y),
                              "+v"(w4[i].z), "+v"(w4[i].w));
    }
}

// ------------------------- transpose mlp_W1 ---------------------------------
__global__ __launch_bounds__(256) void transpose_w1(
    const float* __restrict__ W1, float* __restrict__ W1T)
{
    int idx = blockIdx.x * 256 + threadIdx.x;
    if (idx >= 100 * 1024) return;
    int n = idx / 1024, j = idx % 1024;
    W1T[j * 100 + n] = W1[idx];
}

// ---------------------- A = h1 Wh^T + b1, B = h1 Wm^T -----------------------
__global__ __launch_bounds__(256) void ab_kernel(
    const float* __restrict__ h1, const float* __restrict__ W1T,
    const float* __restrict__ b1v,
    float* __restrict__ Ab, float* __restrict__ Bb)
{
    int m0 = blockIdx.x * 16;
    __shared__ float hs[16][512];
    int tid = threadIdx.x;
    for (int idx = tid * 4; idx < 16 * 512; idx += 1024) {
        int r = idx >> 9, cc = idx & 511;
        *(float4*)&hs[r][cc] = *(const float4*)&h1[(size_t)(m0 + r) * 512 + cc];
    }
    __syncthreads();
    bool isB = tid >= 128;
    int n = tid & 127;
    if (n < 100) {
        float acc[16] = {};
        const float* wbase = W1T + (isB ? 512 * 100 : 0) + n;
#pragma unroll 4
        for (int k = 0; k < 512; k++) {
            float wv = wbase[k * 100];
#pragma unroll
            for (int m = 0; m < 16; m++) acc[m] += hs[m][k] * wv;
        }
        float badd = isB ? 0.f : b1v[n];
        float* dst = isB ? Bb : Ab;
#pragma unroll
        for (int m = 0; m < 16; m++) dst[(m0 + m) * 100 + n] = acc[m] + badd;
    }
}

// ------------------------------ pair MLP ------------------------------------
__global__ __launch_bounds__(256) void pair_kernel(
    const float* __restrict__ Ab, const float* __restrict__ Bb,
    const float* __restrict__ W2, const float* __restrict__ b2,
    float* __restrict__ sT)
{
    int i0 = blockIdx.x * 32, j0 = blockIdx.y * 32;
    __shared__ float Ash[32][101];
    __shared__ float Bsh[32][101];
    __shared__ float w2s[100];
    int tid = threadIdx.x;
    for (int idx = tid; idx < 3200; idx += 256) {
        int r = idx / 100, cc = idx % 100;
        Ash[r][cc] = Ab[(i0 + r) * 100 + cc];
        Bsh[r][cc] = Bb[(j0 + r) * 100 + cc];
    }
    if (tid < 100) w2s[tid] = W2[tid];
    __syncthreads();
    float b2v = b2[0];
    int il = (tid & 15) * 2, jl = (tid >> 4) * 2;
    float a00 = 0.f, a01 = 0.f, a10 = 0.f, a11 = 0.f;
#pragma unroll 4
    for (int k = 0; k < 100; k++) {
        float wv = w2s[k];
        float x0 = Ash[il][k], x1 = Ash[il + 1][k];
        float y0 = Bsh[jl][k], y1 = Bsh[jl + 1][k];
        a00 += wv * tanh_f(x0 + y0);
        a01 += wv * tanh_f(x0 + y1);
        a10 += wv * tanh_f(x1 + y0);
        a11 += wv * tanh_f(x1 + y1);
    }
    float vals[2][2] = {{a00, a01}, {a10, a11}};
#pragma unroll
    for (int a = 0; a < 2; a++)
#pragma unroll
        for (int b = 0; b < 2; b++) {
            int gi2 = i0 + il + a, gj = j0 + jl + b;
            float v = vals[a][b] + b2v;
            if (gi2 == gj) v = 0.f;
            sT[(size_t)gj * 1024 + gi2] = v;
        }
}

// ------------------------- column stats (softmax) ---------------------------
__global__ __launch_bounds__(256) void colstats(
    const float* __restrict__ sT, float* __restrict__ mx, float* __restrict__ rs)
{
    int j = blockIdx.x;
    const float* row = sT + (size_t)j * 1024;
    int tid = threadIdx.x;
    __shared__ float red[256];
    float m = -INFINITY;
    for (int i = tid; i < 1024; i += 256) m = fmaxf(m, row[i]);
    red[tid] = m; __syncthreads();
    for (int s = 128; s > 0; s >>= 1) {
        if (tid < s) red[tid] = fmaxf(red[tid], red[tid + s]);
        __syncthreads();
    }
    float mxv = red[0];
    __syncthreads();
    float ssum = 0.f;
    for (int i = tid; i < 1024; i += 256) ssum += exp2f((row[i] - mxv) * L2E);
    red[tid] = ssum; __syncthreads();
    for (int s = 128; s > 0; s >>= 1) {
        if (tid < s) red[tid] += red[tid + s];
        __syncthreads();
    }
    if (tid == 0) { mx[j] = mxv; rs[j] = 1.f / red[0]; }
}

// ----------------------- normalize + transpose write ------------------------
__global__ __launch_bounds__(256) void writeout(
    const float* __restrict__ sT, const float* __restrict__ mx,
    const float* __restrict__ rs, float* __restrict__ out)
{
    int i0 = blockIdx.x * 32, j0 = blockIdx.y * 32;
    __shared__ float til[32][33];
    int tid = threadIdx.x;
    int r = tid >> 3, c4 = (tid & 7) * 4;
    float4 v = *(const float4*)&sT[(size_t)(j0 + r) * 1024 + i0 + c4];
    til[r][c4 + 0] = v.x; til[r][c4 + 1] = v.y;
    til[r][c4 + 2] = v.z; til[r][c4 + 3] = v.w;
    __syncthreads();
    float4 o;
    float* op = &out[(size_t)(i0 + r) * 1024 + j0 + c4];
    o.x = exp2f((til[c4 + 0][r] - mx[j0 + c4 + 0]) * L2E) * rs[j0 + c4 + 0];
    o.y = exp2f((til[c4 + 1][r] - mx[j0 + c4 + 1]) * L2E) * rs[j0 + c4 + 1];
    o.z = exp2f((til[c4 + 2][r] - mx[j0 + c4 + 2]) * L2E) * rs[j0 + c4 + 2];
    o.w = exp2f((til[c4 + 3][r] - mx[j0 + c4 + 3]) * L2E) * rs[j0 + c4 + 3];
    *(float4*)op = o;
}

// ---------------------------------------------------------------------------
extern "C" void kernel_launch(void* const* d_in, const int* in_sizes, int n_in,
                              void* d_out, int out_size, void* d_ws, size_t ws_size,
                              hipStream_t stream)
{
    const float* word_table = (const float*)d_in[0];
    const float* pos_table  = (const float*)d_in[1];
    const float* l0f_Wih = (const float*)d_in[2];
    const float* l0f_Whh = (const float*)d_in[3];
    const float* l0f_b   = (const float*)d_in[4];
    const float* l0b_Wih = (const float*)d_in[5];
    const float* l0b_Whh = (const float*)d_in[6];
    const float* l0b_b   = (const float*)d_in[7];
    const float* l1f_Wih = (const float*)d_in[8];
    const float* l1f_Whh = (const float*)d_in[9];
    const float* l1f_b   = (const float*)d_in[10];
    const float* l1b_Wih = (const float*)d_in[11];
    const float* l1b_Whh = (const float*)d_in[12];
    const float* l1b_b   = (const float*)d_in[13];
    const float* mlp_W1  = (const float*)d_in[14];
    const float* mlp_b1  = (const float*)d_in[15];
    const float* mlp_W2  = (const float*)d_in[16];
    const float* mlp_b2  = (const float*)d_in[17];
    const int*   word_idx = (const int*)d_in[18];
    const int*   pos_idx  = (const int*)d_in[19];
    float* out = (float*)d_out;

    float* ws = (float*)d_ws;
    const size_t OFF_X   = 0;            // 1024*576
    const size_t OFF_XWF = 589824;       // 1024*1024
    const size_t OFF_XWB = 1638400;      // 1024*1024
    const size_t OFF_H0  = 2686976;      // 1024*512
    const size_t OFF_H1  = 3211264;      // 1024*512
    const size_t OFF_W1T = 3735552;      // 1024*100
    const size_t OFF_A   = 3837952;      // 1024*100
    const size_t OFF_B   = 3940352;      // 1024*100
    const size_t OFF_ST  = 4042752;      // 1024*1024
    const size_t OFF_MX  = 5091328;      // 1024
    const size_t OFF_RS  = 5092352;      // 1024
    const size_t OFF_HX  = 5095424;      // 2 scans * 1024 u64 (= 4096 floats)

    float* x   = ws + OFF_X;
    float* xwf = ws + OFF_XWF;
    float* xwb = ws + OFF_XWB;
    float* h0  = ws + OFF_H0;
    float* h1  = ws + OFF_H1;
    float* w1t = ws + OFF_W1T;
    float* Ab  = ws + OFF_A;
    float* Bb  = ws + OFF_B;
    float* sT  = ws + OFF_ST;
    float* mx  = ws + OFF_MX;
    float* rs  = ws + OFF_RS;
    unsigned long long* hx0 = (unsigned long long*)(ws + OFF_HX);
    unsigned long long* hx1 = hx0 + 1024;

    // zero tagged slots so replays never consume stale tags
    hipMemsetAsync(hx0, 0, 2048 * sizeof(unsigned long long), stream);

    embed_kernel<<<(1024 * 576 + 255) / 256, 256, 0, stream>>>(
        word_table, pos_table, word_idx, pos_idx, x);

    transpose_w1<<<(100 * 1024 + 255) / 256, 256, 0, stream>>>(mlp_W1, w1t);

    gemm_bias<<<dim3(16, 16, 2), 256, 0, stream>>>(
        x, l0f_Wih, l0b_Wih, l0f_b, l0b_b, xwf, xwb, 1024, 1024, 576);

    lstm_scan<<<8, 512, 0, stream>>>(
        xwf, xwb, l0f_Whh, l0b_Whh, h0, hx0);

    gemm_bias<<<dim3(16, 16, 2), 256, 0, stream>>>(
        h0, l1f_Wih, l1b_Wih, l1f_b, l1b_b, xwf, xwb, 1024, 1024, 512);

    lstm_scan<<<8, 512, 0, stream>>>(
        xwf, xwb, l1f_Whh, l1b_Whh, h1, hx1);

    ab_kernel<<<64, 256, 0, stream>>>(h1, w1t, mlp_b1, Ab, Bb);

    pair_kernel<<<dim3(32, 32), 256, 0, stream>>>(Ab, Bb, mlp_W2, mlp_b2, sT);

    colstats<<<1024, 256, 0, stream>>>(sT, mx, rs);

    writeout<<<dim3(32, 32), 256, 0, stream>>>(sT, mx, rs, out);
}